// Round 4
// baseline (66.246 us; speedup 1.0000x reference)
//
#include <hip/hip_runtime.h>
#include <hip/hip_bf16.h>

typedef __bf16 bf16x8 __attribute__((ext_vector_type(8)));
typedef float  f32x4  __attribute__((ext_vector_type(4)));

#define B_ROWS 8192
#define IN_DIM 256
#define OUT_DIM 32
#define NCLS 50
#define INV_T (1.0f / 0.6f)

#define CVT_BLOCKS 1024  // 8192*256 / (256 threads * 8 elems)
#define CGRP 5           // classes per block
#define NGRP 10          // 50 / CGRP
#define MBLKS 128        // 8192 / 64 rows per block

// Fused prep: blocks [0,1024) convert x f32->bf16; blocks [1024,1074) build
// W'[c,o,i] = bf16(W[c,o,i] * alpha_norm[c,i]).
__global__ __launch_bounds__(256) void prep(const float* __restrict__ x,
                                            const float* __restrict__ w,
                                            __bf16* __restrict__ xb,
                                            __bf16* __restrict__ wb) {
    int bid = blockIdx.x;
    if (bid < CVT_BLOCKS) {
        int i = (bid * 256 + threadIdx.x) * 8;
        float4 v0 = *reinterpret_cast<const float4*>(x + i);
        float4 v1 = *reinterpret_cast<const float4*>(x + i + 4);
        bf16x8 r;
        r[0] = (__bf16)v0.x; r[1] = (__bf16)v0.y; r[2] = (__bf16)v0.z; r[3] = (__bf16)v0.w;
        r[4] = (__bf16)v1.x; r[5] = (__bf16)v1.y; r[6] = (__bf16)v1.z; r[7] = (__bf16)v1.w;
        *reinterpret_cast<bf16x8*>(xb + i) = r;
    } else {
        int c = bid - CVT_BLOCKS;
        int i = threadIdx.x;  // IN index
        const float* wc = w + (size_t)c * OUT_DIM * IN_DIM;
        float g = 0.f;
#pragma unroll
        for (int o = 0; o < OUT_DIM; ++o) g += fabsf(wc[o * IN_DIM + i]);
        float m = g;
#pragma unroll
        for (int s = 1; s < 64; s <<= 1) m = fmaxf(m, __shfl_xor(m, s));
        __shared__ float wm[4];
        if ((threadIdx.x & 63) == 0) wm[threadIdx.x >> 6] = m;
        __syncthreads();
        m = fmaxf(fmaxf(wm[0], wm[1]), fmaxf(wm[2], wm[3]));
        float an = __expf((g - m) * INV_T);
        __bf16* wbc = wb + (size_t)c * OUT_DIM * IN_DIM;
#pragma unroll
        for (int o = 0; o < OUT_DIM; ++o)
            wbc[o * IN_DIM + i] = (__bf16)(wc[o * IN_DIM + i] * an);
    }
}

// Batched GEMM: out[b, c, o] = sum_i xb[b,i]*wb[c,o,i] + bias[c,o]
// grid = 128 m-blocks * 10 class-groups. Wave owns 16 rows; A fragments
// register-resident; W fragments double-buffered (prefetch ci+1 during ci).
// __launch_bounds__(256,1): allow big VGPR budget so nothing is rematerialized.
__global__ __launch_bounds__(256, 1) void gemm(const __bf16* __restrict__ xb,
                                               const __bf16* __restrict__ wb,
                                               const float* __restrict__ bias,
                                               float* __restrict__ out) {
    int bid = blockIdx.x;
    int mblk = bid & (MBLKS - 1);
    int cg = bid >> 7;            // 0..9
    int c0 = cg * CGRP;
    int lane = threadIdx.x & 63;
    int wave = threadIdx.x >> 6;
    int m_base = mblk * 64 + wave * 16;
    int l15 = lane & 15;
    int g = lane >> 4;
    int obase = g * 4;

    // A fragments: lane holds x[b=m_base+l15][k=g*8+j+32*kk]
    const __bf16* ap = xb + (size_t)(m_base + l15) * IN_DIM + g * 8;
    bf16x8 afrag[8];
#pragma unroll
    for (int kk = 0; kk < 8; ++kk)
        afrag[kk] = *reinterpret_cast<const bf16x8*>(ap + kk * 32);

    // W fragment double buffer: [buf][kk] = o-rows l15 (0..15), [buf][8+kk] = 16+l15
    bf16x8 wf[2][16];
    auto loadw = [&](int buf, int c) {
        const __bf16* bp = wb + ((size_t)c * OUT_DIM + l15) * IN_DIM + g * 8;
#pragma unroll
        for (int kk = 0; kk < 8; ++kk) {
            wf[buf][kk]     = *reinterpret_cast<const bf16x8*>(bp + kk * 32);
            wf[buf][8 + kk] = *reinterpret_cast<const bf16x8*>(bp + 16 * IN_DIM + kk * 32);
        }
    };

    loadw(0, c0);

    float* orow = out + (size_t)(m_base + l15) * (NCLS * OUT_DIM);

#pragma unroll
    for (int ci = 0; ci < CGRP; ++ci) {
        int cur = ci & 1;
        if (ci + 1 < CGRP) loadw(cur ^ 1, c0 + ci + 1);

        int c = c0 + ci;
        f32x4 acc0 = {0.f, 0.f, 0.f, 0.f};
        f32x4 acc1 = {0.f, 0.f, 0.f, 0.f};
#pragma unroll
        for (int kk = 0; kk < 8; ++kk) {
            acc0 = __builtin_amdgcn_mfma_f32_16x16x32_bf16(wf[cur][kk],     afrag[kk], acc0, 0, 0, 0);
            acc1 = __builtin_amdgcn_mfma_f32_16x16x32_bf16(wf[cur][8 + kk], afrag[kk], acc1, 0, 0, 0);
        }
        float4 bv0 = *reinterpret_cast<const float4*>(bias + c * OUT_DIM + obase);
        float4 bv1 = *reinterpret_cast<const float4*>(bias + c * OUT_DIM + 16 + obase);
        acc0[0] += bv0.x; acc0[1] += bv0.y; acc0[2] += bv0.z; acc0[3] += bv0.w;
        acc1[0] += bv1.x; acc1[1] += bv1.y; acc1[2] += bv1.z; acc1[3] += bv1.w;
        float* p = orow + c * OUT_DIM;
        __builtin_nontemporal_store(acc0, reinterpret_cast<f32x4*>(p + obase));
        __builtin_nontemporal_store(acc1, reinterpret_cast<f32x4*>(p + 16 + obase));
    }
}

extern "C" void kernel_launch(void* const* d_in, const int* in_sizes, int n_in,
                              void* d_out, int out_size, void* d_ws, size_t ws_size,
                              hipStream_t stream) {
    const float* x    = (const float*)d_in[0];
    const float* w    = (const float*)d_in[1];
    const float* bias = (const float*)d_in[2];
    float* out = (float*)d_out;

    __bf16* xb = (__bf16*)d_ws;                       // 8192*256 bf16 = 4 MB
    __bf16* wb = xb + (size_t)B_ROWS * IN_DIM;        // 50*32*256 bf16 = 0.8 MB

    prep<<<CVT_BLOCKS + NCLS, 256, 0, stream>>>(x, w, xb, wb);
    gemm<<<MBLKS * NGRP, 256, 0, stream>>>(xb, wb, bias, out);
}

// Round 5
// 58.251 us; speedup vs baseline: 1.1373x; 1.1373x over previous
//
#include <hip/hip_runtime.h>
#include <hip/hip_bf16.h>

typedef __bf16 bf16x8 __attribute__((ext_vector_type(8)));
typedef float  f32x4  __attribute__((ext_vector_type(4)));

#define B_ROWS 8192
#define IN_DIM 256
#define OUT_DIM 32
#define NCLS 50
#define INV_T (1.0f / 0.6f)

#define CVT_BLOCKS 1024  // x cvt: 8192*256 / (256*8)
#define PG_BLOCKS 400    // partial gamma: 50 classes * 8 o-octs

// k1: blocks [0,1024) convert x f32->bf16; blocks [1024,1424) partial gamma:
// partial[c*8+oct][i] = sum_{o in oct*4..oct*4+3} |W[c,o,i]|
__global__ __launch_bounds__(256) void k1_cvt_partial(const float* __restrict__ x,
                                                      const float* __restrict__ w,
                                                      __bf16* __restrict__ xb,
                                                      float* __restrict__ partial) {
    int bid = blockIdx.x;
    if (bid < CVT_BLOCKS) {
        int i = (bid * 256 + threadIdx.x) * 8;
        float4 v0 = *reinterpret_cast<const float4*>(x + i);
        float4 v1 = *reinterpret_cast<const float4*>(x + i + 4);
        bf16x8 r;
        r[0] = (__bf16)v0.x; r[1] = (__bf16)v0.y; r[2] = (__bf16)v0.z; r[3] = (__bf16)v0.w;
        r[4] = (__bf16)v1.x; r[5] = (__bf16)v1.y; r[6] = (__bf16)v1.z; r[7] = (__bf16)v1.w;
        *reinterpret_cast<bf16x8*>(xb + i) = r;
    } else {
        int p = bid - CVT_BLOCKS;        // 0..399
        int c = p >> 3, oct = p & 7;
        int i = threadIdx.x;
        const float* wp = w + ((size_t)(c * OUT_DIM + oct * 4)) * IN_DIM + i;
        float g = fabsf(wp[0]) + fabsf(wp[IN_DIM]) + fabsf(wp[2 * IN_DIM]) + fabsf(wp[3 * IN_DIM]);
        partial[(size_t)p * IN_DIM + i] = g;
    }
}

// k2: 50 blocks. gamma[c,i] = sum_oct partial; alpha[c,i] = exp((g - max_i g)/T)
__global__ __launch_bounds__(256) void k2_alpha(const float* __restrict__ partial,
                                                float* __restrict__ alpha) {
    int c = blockIdx.x;
    int i = threadIdx.x;
    float g = 0.f;
#pragma unroll
    for (int oct = 0; oct < 8; ++oct)
        g += partial[(size_t)(c * 8 + oct) * IN_DIM + i];
    float m = g;
#pragma unroll
    for (int s = 1; s < 64; s <<= 1) m = fmaxf(m, __shfl_xor(m, s));
    __shared__ float wm[4];
    if ((threadIdx.x & 63) == 0) wm[threadIdx.x >> 6] = m;
    __syncthreads();
    m = fmaxf(fmaxf(wm[0], wm[1]), fmaxf(wm[2], wm[3]));
    alpha[(size_t)c * IN_DIM + i] = __expf((g - m) * INV_T);
}

// k3: 200 blocks. W'[c,o,i] = bf16(W[c,o,i] * alpha[c,i]), 8 i's per thread
__global__ __launch_bounds__(256) void k3_wscale(const float* __restrict__ w,
                                                 const float* __restrict__ alpha,
                                                 __bf16* __restrict__ wb) {
    int tid = blockIdx.x * 256 + threadIdx.x;   // 0..51199
    int r = tid >> 5;                            // (c*32+o) row, 0..1599
    int i0 = (tid & 31) * 8;
    int c = r >> 5;
    const float* wp = w + (size_t)r * IN_DIM + i0;
    const float* al = alpha + (size_t)c * IN_DIM + i0;
    float4 w0 = *reinterpret_cast<const float4*>(wp);
    float4 w1 = *reinterpret_cast<const float4*>(wp + 4);
    float4 a0 = *reinterpret_cast<const float4*>(al);
    float4 a1 = *reinterpret_cast<const float4*>(al + 4);
    bf16x8 o;
    o[0] = (__bf16)(w0.x * a0.x); o[1] = (__bf16)(w0.y * a0.y);
    o[2] = (__bf16)(w0.z * a0.z); o[3] = (__bf16)(w0.w * a0.w);
    o[4] = (__bf16)(w1.x * a1.x); o[5] = (__bf16)(w1.y * a1.y);
    o[6] = (__bf16)(w1.z * a1.z); o[7] = (__bf16)(w1.w * a1.w);
    *reinterpret_cast<bf16x8*>(wb + (size_t)r * IN_DIM + i0) = o;
}

// GEMM: out[b, c, o] = sum_i xb[b,i]*wb[c,o,i] + bias[c,o]
// grid = 50 classes * 32 chunks. Wave = one class, 64 rows (4 row-groups).
// W' register-resident (pinned); A ping-pong prefetch; sched_barrier(0)
// fences pin the {prefetch -> MFMA -> store} issue order.
__global__ __launch_bounds__(256, 2) void gemm(const __bf16* __restrict__ xb,
                                               const __bf16* __restrict__ wb,
                                               const float* __restrict__ bias,
                                               float* __restrict__ out) {
    int bid = blockIdx.x;
    int c = bid >> 5;           // 0..49
    int chunk = bid & 31;
    int lane = threadIdx.x & 63;
    int wave = threadIdx.x >> 6;
    int l15 = lane & 15;
    int g = lane >> 4;
    int row0 = chunk * 256 + wave * 64;

    // W fragments: lane holds W'[c][o=l15 (+16)][k = g*8+j + 32*kk]
    const __bf16* wp = wb + ((size_t)c * OUT_DIM + l15) * IN_DIM + g * 8;
    bf16x8 W[16];
#pragma unroll
    for (int kk = 0; kk < 8; ++kk) {
        W[kk]     = *reinterpret_cast<const bf16x8*>(wp + kk * 32);
        W[8 + kk] = *reinterpret_cast<const bf16x8*>(wp + 16 * IN_DIM + kk * 32);
    }
#pragma unroll
    for (int kk = 0; kk < 16; ++kk)
        asm volatile("" : "+v"(W[kk]));  // def-pin: no remat, stays resident

    const __bf16* ap = xb + (size_t)(row0 + l15) * IN_DIM + g * 8;
    bf16x8 A0[8], A1[8];
#pragma unroll
    for (int kk = 0; kk < 8; ++kk)
        A0[kk] = *reinterpret_cast<const bf16x8*>(ap + kk * 32);

    float4 bv0 = *reinterpret_cast<const float4*>(bias + c * OUT_DIM + g * 4);
    float4 bv1 = *reinterpret_cast<const float4*>(bias + c * OUT_DIM + 16 + g * 4);
    float* op = out + (size_t)(row0 + l15) * (NCLS * OUT_DIM) + c * OUT_DIM + g * 4;

    __builtin_amdgcn_sched_barrier(0);

#define PREFETCH(DST, R)                                                        \
    _Pragma("unroll") for (int kk = 0; kk < 8; ++kk)                            \
        DST[kk] = *reinterpret_cast<const bf16x8*>(ap + (R) * 16 * IN_DIM + kk * 32);

#define COMPUTE(SRC, R) {                                                       \
        f32x4 acc0 = {bv0.x, bv0.y, bv0.z, bv0.w};                              \
        f32x4 acc1 = {bv1.x, bv1.y, bv1.z, bv1.w};                              \
        _Pragma("unroll") for (int kk = 0; kk < 8; ++kk) {                      \
            acc0 = __builtin_amdgcn_mfma_f32_16x16x32_bf16(W[kk],     SRC[kk], acc0, 0, 0, 0); \
            acc1 = __builtin_amdgcn_mfma_f32_16x16x32_bf16(W[8 + kk], SRC[kk], acc1, 0, 0, 0); \
        }                                                                       \
        *reinterpret_cast<f32x4*>(op + (size_t)(R) * 16 * (NCLS * OUT_DIM)) = acc0;      \
        *reinterpret_cast<f32x4*>(op + (size_t)(R) * 16 * (NCLS * OUT_DIM) + 16) = acc1; \
    }

    PREFETCH(A1, 1)
    __builtin_amdgcn_sched_barrier(0);
    COMPUTE(A0, 0)
    PREFETCH(A0, 2)
    __builtin_amdgcn_sched_barrier(0);
    COMPUTE(A1, 1)
    PREFETCH(A1, 3)
    __builtin_amdgcn_sched_barrier(0);
    COMPUTE(A0, 2)
    COMPUTE(A1, 3)

#undef PREFETCH
#undef COMPUTE
}

extern "C" void kernel_launch(void* const* d_in, const int* in_sizes, int n_in,
                              void* d_out, int out_size, void* d_ws, size_t ws_size,
                              hipStream_t stream) {
    const float* x    = (const float*)d_in[0];
    const float* w    = (const float*)d_in[1];
    const float* bias = (const float*)d_in[2];
    float* out = (float*)d_out;

    __bf16* xb    = (__bf16*)d_ws;                              // 4 MB
    __bf16* wb    = xb + (size_t)B_ROWS * IN_DIM;               // 0.8 MB
    float* partial = (float*)(wb + (size_t)NCLS * OUT_DIM * IN_DIM);  // 400 KB
    float* alpha   = partial + (size_t)PG_BLOCKS * IN_DIM;            // 50 KB

    k1_cvt_partial<<<CVT_BLOCKS + PG_BLOCKS, 256, 0, stream>>>(x, w, xb, partial);
    k2_alpha<<<NCLS, 256, 0, stream>>>(partial, alpha);
    k3_wscale<<<200, 256, 0, stream>>>(w, alpha, wb);
    gemm<<<NCLS * 32, 256, 0, stream>>>(xb, wb, bias, out);
}